// Round 17
// baseline (140.701 us; speedup 1.0000x reference)
//
#include <hip/hip_runtime.h>
#include <stdint.h>
#include <stddef.h>

// SplitConv4Pim forward on MI355X — INT8 formulation.
// w_q = (q-2)*64*s_ic exact int8; s folded into x' (int8, per-tensor sxp).
// psum = sxp * int32-MFMA dot.
// R17 = R16 with the FULL-block path moved to mfma_i32_32x32x32_i8 (11.7%
// faster rate, 8 vs 16 MFMA/step). P1 bakes TWO weight layouts: 32x32-frag
// order (full path) and 16x16-frag order (tiny path, verbatim R16).
// ws: [wq32 i8: 2,359,296][wq16 i8: 2,359,296][xt2 i8: 13,778,944]

typedef int i32x4  __attribute__((ext_vector_type(4)));
typedef int i32x16 __attribute__((ext_vector_type(16)));

#define WS_W16_OFF 2359296
#define WS_XT_OFF  4718592
#define NPIX 53824            // 16 * 58 * 58 padded pixels
#define CLIP 5.5f

__device__ __forceinline__ void gload16(const void* g, void* l) {
  __builtin_amdgcn_global_load_lds(
      (const __attribute__((address_space(1))) uint32_t*)g,
      (__attribute__((address_space(3))) uint32_t*)l, 16, 0, 0);
}

// ---- prep: blocks 0..1023 weight-quant+bake x2; 1024..1951 x-quant ----
// wq32 panel p = kk*4+ocb: chunk = g*256 + ksub*128 + ocf32*64 + lane32,
//   lane32 = (o&31) | ((k32>>4)<<5), byte = k32&15  (k64 = ic&63).
// wq16 panel p: chunk = g*256 + ocf16*64 + lane16 (R16 layout).
// xt2: [icq 16][pix NPIX][16 i8].
__global__ void prep_k(const float* __restrict__ w, const float* __restrict__ wsc,
                       int8_t* __restrict__ wq32, int8_t* __restrict__ wq16,
                       const float* __restrict__ x, int8_t* __restrict__ xt2) {
  __shared__ char  tile[56 * 272];
  __shared__ float wl[2304];
  __shared__ float facs[8];
  const int t = threadIdx.x;                  // 256 threads
  if (blockIdx.x < 1024) {
    const int o = blockIdx.x;
    for (int i = t; i < 2304; i += 256) wl[i] = w[o * 2304 + i];
    __syncthreads();
    const int ic = t;
    const float s = wsc[ic >> 5];
    const int g = o >> 8, ocb = (o >> 6) & 3;
    // 16x16 placement pieces
    const int ocf16 = (o >> 4) & 3, row16 = o & 15;
    const int lhi = (ic >> 4) & 3, j16 = ic & 15;
    const int lane16 = lhi * 16 + row16;
    // 32x32 placement pieces
    const int ocf32 = (o >> 5) & 1, ocr = o & 31;
    const int icb64 = ic >> 6, k64 = ic & 63;
    const int ksub = k64 >> 5, k32 = k64 & 31;
    const int lane32 = ocr + ((k32 >> 4) << 5);
    const int j32 = k32 & 15;
#pragma unroll
    for (int kpos = 0; kpos < 9; ++kpos) {
      float wi = rintf(wl[ic * 9 + kpos] / s);
      wi = fminf(127.f, fmaxf(-128.f, wi));
      int q = (((int)wi + 128) >> 6) & 3;
      int8_t v = (int8_t)(q - 2);
      int p = (kpos * 4 + icb64) * 4 + ocb;
      wq16[(size_t)p * 16384 + (g * 256 + ocf16 * 64 + lane16) * 16 + j16] = v;
      wq32[(size_t)p * 16384 + (g * 256 + ksub * 128 + ocf32 * 64 + lane32) * 16 + j32] = v;
    }
    return;
  }
  // ---- x path ----
  int pb = blockIdx.x - 1024;                 // 0..927
  int b  = pb / 58;
  int yo = pb % 58;
  const int pixrow = (b * 58 + yo) * 58;
  if (yo == 0 || yo == 57) {                  // top/bottom pad rows
    int icq = t >> 4, xos = t & 15;
    i32x4 z = {0, 0, 0, 0};
    for (int xo = xos; xo < 58; xo += 16)
      *(i32x4*)(xt2 + ((size_t)(icq * NPIX + pixrow + xo) << 4)) = z;
    return;
  }
  if (t < 8) {                                // per-ic32 x' scale factors
    float maxs = wsc[0];
    for (int i = 1; i < 8; ++i) maxs = fmaxf(maxs, wsc[i]);
    facs[t] = wsc[t] * 127.f / (CLIP * maxs);
  }
  __syncthreads();
  const float* src = x + (size_t)b * 256 * 3136 + (yo - 1) * 56;
  for (int i = 0; i < 56 * 256; i += 256) {
    int lin = i + t;
    int c  = lin / 56;
    int xx = lin - c * 56;
    float v = rintf(src[c * 3136 + xx] * facs[c >> 5]);
    v = fminf(127.f, fmaxf(-127.f, v));
    tile[xx * 272 + c] = (int8_t)v;
  }
  __syncthreads();
  {
    int icq = t >> 4, xos = t & 15;
    for (int xo = xos; xo < 58; xo += 16) {
      i32x4 v = {0, 0, 0, 0};
      if (xo >= 1 && xo <= 56) v = *(const i32x4*)&tile[(xo - 1) * 272 + icq * 16];
      *(i32x4*)(xt2 + ((size_t)(icq * NPIX + pixrow + xo) << 4)) = v;
    }
  }
}

// ---- main conv ----
// grid 1664: bid<128 tiny (32m, 16x16 MFMA, wq16) FIRST; bid>=128 full
// (128m x 64oc x 4g, 32x32x32_i8, wq32; 384 mt x 4 ocb = 3 exact rounds).
// 512 thr = 8 waves (4g x 2mpos). Triple-buffer, counted vmcnt(3), setprio,
// fully unrolled 36-step K-loop. Epilogue reduce: padded [g][m][19 u32].
__global__ __launch_bounds__(512, 4)
void conv_q_k(const int8_t* __restrict__ xt2, const int8_t* __restrict__ wq32,
              const int8_t* __restrict__ wq16, const float* __restrict__ ps,
              const float* __restrict__ wsc, float* __restrict__ out) {
  __shared__ alignas(16) char lds[3 * 24576];

  const int tid  = threadIdx.x;
  const int lane = tid & 63;
  const int wave = tid >> 6;
  const int g    = wave >> 1;                   // group 0..3
  const int mpos = wave & 1;
  const int rr = lane & 15, hi = lane >> 4;
  const int bid = blockIdx.x;

  float maxs = wsc[0];
#pragma unroll
  for (int i = 1; i < 8; ++i) maxs = fmaxf(maxs, wsc[i]);
  const float sxp = CLIP * 64.f * maxs / 127.f;

  if (bid >= 128) {
    // ============ FULL BLOCK: 128m x 64oc x 4g, 32x32x32_i8 ============
    const int f   = bid - 128;
    const int xcd = f & 7;
    const int u   = f >> 3;                     // 0..191
    const int mt  = (xcd & 3) * 96 + (u >> 1);  // 0..383
    const int ocb = ((xcd >> 2) << 1) + (u & 1);
    const int m0  = mt << 7;

    const int8_t* const aSrc = wq32 + (size_t)ocb * 16384 + tid * 16;
    const int8_t* bSrc;
    {
      // B chunk tid: ksub = tid>>8, mfrag = (tid>>6)&3, lane lS = tid&63
      int lS = tid & 63;
      int gm = m0 + ((tid >> 6) & 3) * 32 + (lS & 31);
      int b = gm / 3136, rem = gm - b * 3136;
      int oy = rem / 56, ox = rem - oy * 56;
      int pbase = (b * 58 + oy) * 58 + ox;
      int icq = (tid >> 8) * 2 + (lS >> 5);
      bSrc = xt2 + (((size_t)icq * NPIX + pbase) << 4);
    }
    char* const ldDst = lds + tid * 16;
    // read offsets: A chunk = g*256 + ksub*128 + ocf*64 + lane
    const int aRd = g * 4096 + lane * 16;       // + ksub*2048 + ocf*1024
    const int bRd = 16384 + (mpos * 2) * 1024 + lane * 16;  // + ksub*4096 + jm*1024

    i32x16 acc[2][2];                           // [ocf][jm]
#pragma unroll
    for (int i = 0; i < 2; ++i)
#pragma unroll
      for (int j = 0; j < 2; ++j)
#pragma unroll
        for (int k = 0; k < 16; ++k) acc[i][j][k] = 0;

    auto STAGE = [&](int kk, int buf) {
      const int kpos = kk >> 2, icb64 = kk & 3;
      const int ky = kpos / 3, kx = kpos - ky * 3;
      const size_t aof = (size_t)kk * 65536;
      const int    xof = ((icb64 * 4 * NPIX) << 4) + ((ky * 58 + kx) << 4);
      char* base = ldDst + buf * 24576;
      gload16(aSrc + aof,        base);
      gload16(aSrc + aof + 8192, base + 8192);
      gload16(bSrc + xof,        base + 16384);
    };

#pragma unroll
    for (int pt = 0; pt < 2; ++pt) STAGE(pt, pt);
    asm volatile("s_waitcnt vmcnt(3)" ::: "memory");
    __builtin_amdgcn_s_barrier();
    __builtin_amdgcn_sched_barrier(0);

#pragma unroll
    for (int t = 0; t < 36; ++t) {
      const int cur = t % 3;
      const int nxt = (t + 2) % 3;
      if (t + 2 < 36) STAGE(t + 2, nxt);
      const char* bp = lds + cur * 24576;
      i32x4 av[2][2], bv[2][2];                 // [ocf][ksub], [jm][ksub]
#pragma unroll
      for (int ocf = 0; ocf < 2; ++ocf)
#pragma unroll
        for (int ks = 0; ks < 2; ++ks)
          av[ocf][ks] = *(const i32x4*)(bp + aRd + ks * 2048 + ocf * 1024);
#pragma unroll
      for (int jm = 0; jm < 2; ++jm)
#pragma unroll
        for (int ks = 0; ks < 2; ++ks)
          bv[jm][ks] = *(const i32x4*)(bp + bRd + ks * 4096 + jm * 1024);
      __builtin_amdgcn_s_setprio(1);
#pragma unroll
      for (int ks = 0; ks < 2; ++ks)
#pragma unroll
        for (int ocf = 0; ocf < 2; ++ocf)
#pragma unroll
          for (int jm = 0; jm < 2; ++jm)
            acc[ocf][jm] = __builtin_amdgcn_mfma_i32_32x32x32_i8(
                av[ocf][ks], bv[jm][ks], acc[ocf][jm], 0, 0, 0);
      __builtin_amdgcn_s_setprio(0);
      if (t < 34) asm volatile("s_waitcnt vmcnt(3)" ::: "memory");
      else        asm volatile("s_waitcnt vmcnt(0)" ::: "memory");
      __builtin_amdgcn_s_barrier();
      __builtin_amdgcn_sched_barrier(0);
    }
    __syncthreads();

    // epilogue: quantize -> int8 pack -> LDS [4g][128 m][19 u32] -> reduce.
    // D layout (32x32): col=lane&31 -> m, row=(reg&3)+8*(reg>>2)+4*(lane>>5) -> oc.
    {
      const float r = sxp / ps[g];
      const int hi32 = lane >> 5;
      const int mlb  = mpos * 64 + (lane & 31);
#pragma unroll
      for (int ocf = 0; ocf < 2; ++ocf)
#pragma unroll
        for (int jm = 0; jm < 2; ++jm)
#pragma unroll
          for (int q4 = 0; q4 < 4; ++q4) {
            uint32_t pk = 0;
#pragma unroll
            for (int rI = 0; rI < 4; ++rI) {
              float q = rintf((float)acc[ocf][jm][4 * q4 + rI] * r);
              q = fminf(127.f, fmaxf(-128.f, q));
              pk |= ((uint32_t)(((int)q) & 255)) << (8 * rI);
            }
            int m_l = mlb + jm * 32;
            int oc4 = ocf * 8 + 2 * q4 + hi32;
            *(uint32_t*)(lds + (g * 2432 + m_l * 19 + oc4) * 4) = pk;
          }
    }
    __syncthreads();
    {
      const int m_l = tid >> 2;                 // 0..127
      const int c   = tid & 3;                  // oc4 base = c*4
      float o[16];
#pragma unroll
      for (int j = 0; j < 16; ++j) o[j] = 0.f;
#pragma unroll
      for (int gg = 0; gg < 4; ++gg) {
        const float spg = ps[gg];
#pragma unroll
        for (int w4 = 0; w4 < 4; ++w4) {
          uint32_t v = *(const uint32_t*)(lds + (gg * 2432 + m_l * 19 + c * 4 + w4) * 4);
#pragma unroll
          for (int b2 = 0; b2 < 4; ++b2)
            o[w4 * 4 + b2] += (float)((int)(int8_t)(v >> (8 * b2))) * spg;
        }
      }
      int gm = m0 + m_l;
      int b = gm / 3136, rem = gm - b * 3136;
      int oy = rem / 56, ox = rem - oy * 56;
      float* ob = out + b * 802816 + oy * 56 + ox;
      const int occ = (ocb << 6) + (c << 4);
#pragma unroll
      for (int j = 0; j < 16; ++j) ob[(occ + j) * 3136] = o[j];
    }
    return;
  }

  // ======= TINY BLOCK: 32m x 64oc x 4g (bid 0..127, FIRST; 16x16, wq16) ====
  {
    const int v   = bid;
    const int mtt = v >> 2;                     // 0..31
    const int ocb = v & 3;
    const int m0  = 49152 + (mtt << 5);

    const int8_t* const aSrc = wq16 + (size_t)ocb * 16384 + tid * 16;
    const int8_t* bSrc;
    {
      int tl = tid & 127;                       // waves 2..7 mirror 0,1 (benign)
      int gm = m0 + ((tl >> 6) << 4) + (tl & 15);
      int b = gm / 3136, rem = gm - b * 3136;
      int oy = rem / 56, ox = rem - oy * 56;
      int pbase = (b * 58 + oy) * 58 + ox;
      bSrc = xt2 + ((((size_t)((tl >> 4) & 3) * NPIX) + pbase) << 4);
    }
    // buffers: [A 16KB][B 2KB] stride 18432, triple
    char* const ldA = lds + tid * 16;
    char* const ldB = lds + 16384 + (tid & 127) * 16;
    const int aRd = g * 4096 + lane * 16;                  // + i*1024
    const int bRd = 16384 + mpos * 1024 + lane * 16;       // single j frag

    i32x4 acc[4];                               // [i ocfrag], 1 mfrag
#pragma unroll
    for (int i = 0; i < 4; ++i)
#pragma unroll
      for (int k = 0; k < 4; ++k) acc[i][k] = 0;

    auto STAGE = [&](int kk, int buf) {
      const int kpos = kk >> 2, icb64 = kk & 3;
      const int ky = kpos / 3, kx = kpos - ky * 3;
      const size_t aof = (size_t)kk * 65536;
      const int    xof = ((icb64 * 4 * NPIX) << 4) + ((ky * 58 + kx) << 4);
      char* ba = ldA + buf * 18432;
      gload16(aSrc + aof,        ba);
      gload16(aSrc + aof + 8192, ba + 8192);
      gload16(bSrc + xof, ldB + buf * 18432);   // 2KB, wave-sets redundant
    };

#pragma unroll
    for (int pt = 0; pt < 2; ++pt) STAGE(pt, pt);
    asm volatile("s_waitcnt vmcnt(3)" ::: "memory");
    __builtin_amdgcn_s_barrier();
    __builtin_amdgcn_sched_barrier(0);

#pragma unroll
    for (int t = 0; t < 36; ++t) {
      const int cur = t % 3;
      const int nxt = (t + 2) % 3;
      if (t + 2 < 36) STAGE(t + 2, nxt);
      const char* bp = lds + cur * 18432;
      i32x4 av[4], bv;
#pragma unroll
      for (int i = 0; i < 4; ++i) av[i] = *(const i32x4*)(bp + aRd + i * 1024);
      bv = *(const i32x4*)(bp + bRd);
      __builtin_amdgcn_s_setprio(1);
#pragma unroll
      for (int i = 0; i < 4; ++i)
        acc[i] = __builtin_amdgcn_mfma_i32_16x16x64_i8(av[i], bv, acc[i], 0, 0, 0);
      __builtin_amdgcn_s_setprio(0);
      if (t < 34) asm volatile("s_waitcnt vmcnt(3)" ::: "memory");
      else        asm volatile("s_waitcnt vmcnt(0)" ::: "memory");
      __builtin_amdgcn_s_barrier();
      __builtin_amdgcn_sched_barrier(0);
    }
    __syncthreads();

    // epilogue: int8 LDS [4g][32 m][19 u32] -> reduce (512 thr: 1 u32 each)
    {
      const float r = sxp / ps[g];
#pragma unroll
      for (int i = 0; i < 4; ++i) {
        uint32_t pk = 0;
#pragma unroll
        for (int k = 0; k < 4; ++k) {
          float q = rintf((float)acc[i][k] * r);
          q = fminf(127.f, fmaxf(-128.f, q));
          pk |= ((uint32_t)(((int)q) & 255)) << (8 * k);
        }
        int m_l = mpos * 16 + rr;
        int oc4 = i * 4 + hi;
        *(uint32_t*)(lds + (g * 608 + m_l * 19 + oc4) * 4) = pk;
      }
    }
    __syncthreads();
    {
      const int m_l = tid >> 4;                 // 0..31
      const int oc4 = tid & 15;                 // u32 column
      float o[4] = {0.f, 0.f, 0.f, 0.f};
#pragma unroll
      for (int gg = 0; gg < 4; ++gg) {
        const float spg = ps[gg];
        uint32_t v2 = *(const uint32_t*)(lds + (gg * 608 + m_l * 19 + oc4) * 4);
#pragma unroll
        for (int b2 = 0; b2 < 4; ++b2)
          o[b2] += (float)((int)(int8_t)(v2 >> (8 * b2))) * spg;
      }
      int gm = m0 + m_l;
      int b = gm / 3136, rem = gm - b * 3136;
      int oy = rem / 56, ox = rem - oy * 56;
      float* ob = out + b * 802816 + oy * 56 + ox;
      const int occ = (ocb << 6) + (oc4 << 2);
#pragma unroll
      for (int j = 0; j < 4; ++j) ob[(occ + j) * 3136] = o[j];
    }
  }
}

extern "C" void kernel_launch(void* const* d_in, const int* in_sizes, int n_in,
                              void* d_out, int out_size, void* d_ws, size_t ws_size,
                              hipStream_t stream) {
  const float* x   = (const float*)d_in[0];   // [16,256,56,56]
  const float* w   = (const float*)d_in[1];   // [1024,256,3,3]
  const float* wsc = (const float*)d_in[2];   // [8]
  const float* ps  = (const float*)d_in[3];   // [4]
  float* out = (float*)d_out;                 // [16,256,56,56]
  int8_t* wq32 = (int8_t*)d_ws;
  int8_t* wq16 = (int8_t*)((char*)d_ws + WS_W16_OFF);
  int8_t* xt2  = (int8_t*)((char*)d_ws + WS_XT_OFF);

  prep_k<<<1024 + 928, 256, 0, stream>>>(w, wsc, wq32, wq16, x, xt2);
  conv_q_k<<<1664, 512, 0, stream>>>(xt2, wq32, wq16, ps, wsc, out);
}

// Round 18
// 117.391 us; speedup vs baseline: 1.1986x; 1.1986x over previous
//
#include <hip/hip_runtime.h>
#include <stdint.h>
#include <stddef.h>

// SplitConv4Pim forward on MI355X — INT8 formulation.
// w_q = (q-2)*64*s_ic exact int8; s folded into x' (int8, per-tensor sxp).
// psum = sxp * int32-MFMA dot (mfma_i32_16x16x64_i8).
// R18 = revert to R16 (best verified: 117.4 us total, conv 102.4 us).
// R17's 32x32x32 shape regressed (dependent 2-MFMA chains per acc tile stall
// the longer pipe); 16x16x64 with 16 independent accumulators stays.
// Kept: int8 math, fragment-major LDS (0 main-loop conflicts), triple-buffer
// counted vmcnt(3), full K-unroll, tiny-blocks-first mixed grid, padded
// [g][m][19 u32] epilogue reduce.
// ws: [wq3 i8: 2,359,296 B][xt2 i8: 13,778,944 B]

typedef int i32x4 __attribute__((ext_vector_type(4)));

#define WS_XT_OFF 2359296
#define NPIX 53824            // 16 * 58 * 58 padded pixels
#define CLIP 5.5f

__device__ __forceinline__ void gload16(const void* g, void* l) {
  __builtin_amdgcn_global_load_lds(
      (const __attribute__((address_space(1))) uint32_t*)g,
      (__attribute__((address_space(3))) uint32_t*)l, 16, 0, 0);
}

// ---- prep: blocks 0..1023 weight-quant+bake (block = one o, coalesced);
//      blocks 1024..1951 x-quant+transpose ----
// wq3 panels: p = kk*4+ocb (kk = kpos*4+icb64): [4g][4 ocfrag][64 lane][16 i8].
// xt2: [icq 16][pix NPIX][16 i8].
__global__ void prep_k(const float* __restrict__ w, const float* __restrict__ wsc,
                       int8_t* __restrict__ wq3,
                       const float* __restrict__ x, int8_t* __restrict__ xt2) {
  __shared__ char  tile[56 * 272];
  __shared__ float wl[2304];
  __shared__ float facs[8];
  const int t = threadIdx.x;                  // 256 threads
  if (blockIdx.x < 1024) {
    const int o = blockIdx.x;
    for (int i = t; i < 2304; i += 256) wl[i] = w[o * 2304 + i];
    __syncthreads();
    const int ic = t;
    const float s = wsc[ic >> 5];
    const int g = o >> 8, ocb = (o >> 6) & 3, ocf = (o >> 4) & 3, row = o & 15;
    const int icb64 = ic >> 6, lhi = (ic >> 4) & 3, j = ic & 15;
    const int lane = lhi * 16 + row;
#pragma unroll
    for (int kpos = 0; kpos < 9; ++kpos) {
      float wi = rintf(wl[ic * 9 + kpos] / s);
      wi = fminf(127.f, fmaxf(-128.f, wi));
      int q = (((int)wi + 128) >> 6) & 3;
      int p = (kpos * 4 + icb64) * 4 + ocb;
      wq3[(size_t)p * 16384 + (g * 256 + ocf * 64 + lane) * 16 + j] = (int8_t)(q - 2);
    }
    return;
  }
  // ---- x path ----
  int pb = blockIdx.x - 1024;                 // 0..927
  int b  = pb / 58;
  int yo = pb % 58;
  const int pixrow = (b * 58 + yo) * 58;
  if (yo == 0 || yo == 57) {                  // top/bottom pad rows
    int icq = t >> 4, xos = t & 15;
    i32x4 z = {0, 0, 0, 0};
    for (int xo = xos; xo < 58; xo += 16)
      *(i32x4*)(xt2 + ((size_t)(icq * NPIX + pixrow + xo) << 4)) = z;
    return;
  }
  if (t < 8) {                                // per-ic32 x' scale factors
    float maxs = wsc[0];
    for (int i = 1; i < 8; ++i) maxs = fmaxf(maxs, wsc[i]);
    facs[t] = wsc[t] * 127.f / (CLIP * maxs);
  }
  __syncthreads();
  const float* src = x + (size_t)b * 256 * 3136 + (yo - 1) * 56;
  for (int i = 0; i < 56 * 256; i += 256) {
    int lin = i + t;
    int c  = lin / 56;
    int xx = lin - c * 56;
    float v = rintf(src[c * 3136 + xx] * facs[c >> 5]);
    v = fminf(127.f, fmaxf(-127.f, v));
    tile[xx * 272 + c] = (int8_t)v;
  }
  __syncthreads();
  {
    int icq = t >> 4, xos = t & 15;
    for (int xo = xos; xo < 58; xo += 16) {
      i32x4 v = {0, 0, 0, 0};
      if (xo >= 1 && xo <= 56) v = *(const i32x4*)&tile[(xo - 1) * 272 + icq * 16];
      *(i32x4*)(xt2 + ((size_t)(icq * NPIX + pixrow + xo) << 4)) = v;
    }
  }
}

// ---- main conv ----
// grid 1664: bid<128 tiny (32m, 32 mt x 4 ocb) dispatched FIRST; bid>=128 full
// (128m x 64oc x 4g, 384 mt x 4 ocb = 3 exact rounds of 512 slots).
// 512 thr = 8 waves (4g x 2mpos). Triple-buffer, counted vmcnt(3), setprio,
// fully unrolled 36-step K-loop. Epilogue reduce: padded [g][m][19 u32].
__global__ __launch_bounds__(512, 4)
void conv_q_k(const int8_t* __restrict__ xt2, const int8_t* __restrict__ wq3,
              const float* __restrict__ ps, const float* __restrict__ wsc,
              float* __restrict__ out) {
  __shared__ alignas(16) char lds[3 * 24576];

  const int tid  = threadIdx.x;
  const int lane = tid & 63;
  const int wave = tid >> 6;
  const int g    = wave >> 1;                   // group 0..3
  const int mpos = wave & 1;
  const int rr = lane & 15, hi = lane >> 4;
  const int bid = blockIdx.x;

  float maxs = wsc[0];
#pragma unroll
  for (int i = 1; i < 8; ++i) maxs = fmaxf(maxs, wsc[i]);
  const float sxp = CLIP * 64.f * maxs / 127.f;

  if (bid >= 128) {
    // ================= FULL BLOCK: 128m x 64oc x 4g =================
    // XCD swizzle on f = bid-128 (128%8==0 keeps XCD alignment):
    // 1536 = 8 x 192; per XCD 96 mt x 2 ocb.
    const int f   = bid - 128;
    const int xcd = f & 7;
    const int u   = f >> 3;                     // 0..191
    const int mt  = (xcd & 3) * 96 + (u >> 1);  // 0..383
    const int ocb = ((xcd >> 2) << 1) + (u & 1);
    const int m0  = mt << 7;

    const int8_t* const aSrc = wq3 + (size_t)ocb * 16384 + tid * 16;
    const int8_t* bSrc;
    {
      int gm = m0 + ((tid >> 6) << 4) + (lane & 15);
      int b = gm / 3136, rem = gm - b * 3136;
      int oy = rem / 56, ox = rem - oy * 56;
      int pbase = (b * 58 + oy) * 58 + ox;
      bSrc = xt2 + ((((size_t)(lane >> 4) * NPIX) + pbase) << 4);
    }
    char* const ldDst = lds + tid * 16;
    const int aRd = g * 4096 + lane * 16;                    // + i*1024
    const int bRd = 16384 + (mpos * 4) * 1024 + lane * 16;   // + j*1024

    i32x4 acc[4][4];
#pragma unroll
    for (int i = 0; i < 4; ++i)
#pragma unroll
      for (int j = 0; j < 4; ++j)
#pragma unroll
        for (int k = 0; k < 4; ++k) acc[i][j][k] = 0;

    auto STAGE = [&](int kk, int buf) {
      const int kpos = kk >> 2, icb64 = kk & 3;
      const int ky = kpos / 3, kx = kpos - ky * 3;
      const size_t aof = (size_t)kk * 65536;
      const int    xof = ((icb64 * 4 * NPIX) << 4) + ((ky * 58 + kx) << 4);
      char* base = ldDst + buf * 24576;
      gload16(aSrc + aof,        base);
      gload16(aSrc + aof + 8192, base + 8192);
      gload16(bSrc + xof,        base + 16384);
    };

#pragma unroll
    for (int pt = 0; pt < 2; ++pt) STAGE(pt, pt);
    asm volatile("s_waitcnt vmcnt(3)" ::: "memory");
    __builtin_amdgcn_s_barrier();
    __builtin_amdgcn_sched_barrier(0);

#pragma unroll
    for (int t = 0; t < 36; ++t) {
      const int cur = t % 3;
      const int nxt = (t + 2) % 3;
      if (t + 2 < 36) STAGE(t + 2, nxt);
      const char* bp = lds + cur * 24576;
      i32x4 av[4], bv[4];
#pragma unroll
      for (int i = 0; i < 4; ++i) av[i] = *(const i32x4*)(bp + aRd + i * 1024);
#pragma unroll
      for (int j = 0; j < 4; ++j) bv[j] = *(const i32x4*)(bp + bRd + j * 1024);
      __builtin_amdgcn_s_setprio(1);
#pragma unroll
      for (int i = 0; i < 4; ++i)
#pragma unroll
        for (int j = 0; j < 4; ++j)
          acc[i][j] = __builtin_amdgcn_mfma_i32_16x16x64_i8(av[i], bv[j], acc[i][j], 0, 0, 0);
      __builtin_amdgcn_s_setprio(0);
      if (t < 34) asm volatile("s_waitcnt vmcnt(3)" ::: "memory");
      else        asm volatile("s_waitcnt vmcnt(0)" ::: "memory");
      __builtin_amdgcn_s_barrier();
      __builtin_amdgcn_sched_barrier(0);
    }
    __syncthreads();

    // epilogue: quantize per group -> int8 LDS [4g][128 m][19 u32] -> reduce
    {
      const float r = sxp / ps[g];
#pragma unroll
      for (int i = 0; i < 4; ++i)
#pragma unroll
        for (int j = 0; j < 4; ++j) {
          uint32_t pk = 0;
#pragma unroll
          for (int k = 0; k < 4; ++k) {
            float q = rintf((float)acc[i][j][k] * r);
            q = fminf(127.f, fmaxf(-128.f, q));
            pk |= ((uint32_t)(((int)q) & 255)) << (8 * k);
          }
          int m_l = mpos * 64 + j * 16 + rr;
          int oc4 = i * 4 + hi;
          *(uint32_t*)(lds + (g * 2432 + m_l * 19 + oc4) * 4) = pk;
        }
    }
    __syncthreads();
    {
      const int m_l = tid >> 2;                 // 0..127
      const int c   = tid & 3;                  // oc4 base = c*4
      float o[16];
#pragma unroll
      for (int j = 0; j < 16; ++j) o[j] = 0.f;
#pragma unroll
      for (int gg = 0; gg < 4; ++gg) {
        const float spg = ps[gg];
#pragma unroll
        for (int w4 = 0; w4 < 4; ++w4) {
          uint32_t v = *(const uint32_t*)(lds + (gg * 2432 + m_l * 19 + c * 4 + w4) * 4);
#pragma unroll
          for (int b2 = 0; b2 < 4; ++b2)
            o[w4 * 4 + b2] += (float)((int)(int8_t)(v >> (8 * b2))) * spg;
        }
      }
      int gm = m0 + m_l;
      int b = gm / 3136, rem = gm - b * 3136;
      int oy = rem / 56, ox = rem - oy * 56;
      float* ob = out + b * 802816 + oy * 56 + ox;
      const int occ = (ocb << 6) + (c << 4);
#pragma unroll
      for (int j = 0; j < 16; ++j) ob[(occ + j) * 3136] = o[j];
    }
    return;
  }

  // ================= TINY BLOCK: 32m x 64oc x 4g (bid 0..127, FIRST) =======
  {
    const int v   = bid;
    const int mtt = v >> 2;                     // 0..31
    const int ocb = v & 3;
    const int m0  = 49152 + (mtt << 5);

    const int8_t* const aSrc = wq3 + (size_t)ocb * 16384 + tid * 16;
    const int8_t* bSrc;
    {
      int tl = tid & 127;                       // waves 2..7 mirror 0,1 (benign)
      int gm = m0 + ((tl >> 6) << 4) + (tl & 15);
      int b = gm / 3136, rem = gm - b * 3136;
      int oy = rem / 56, ox = rem - oy * 56;
      int pbase = (b * 58 + oy) * 58 + ox;
      bSrc = xt2 + ((((size_t)((tl >> 4) & 3) * NPIX) + pbase) << 4);
    }
    // buffers: [A 16KB][B 2KB] stride 18432, triple
    char* const ldA = lds + tid * 16;
    char* const ldB = lds + 16384 + (tid & 127) * 16;
    const int aRd = g * 4096 + lane * 16;                  // + i*1024
    const int bRd = 16384 + mpos * 1024 + lane * 16;       // single j frag

    i32x4 acc[4];                               // [i ocfrag], 1 mfrag
#pragma unroll
    for (int i = 0; i < 4; ++i)
#pragma unroll
      for (int k = 0; k < 4; ++k) acc[i][k] = 0;

    auto STAGE = [&](int kk, int buf) {
      const int kpos = kk >> 2, icb64 = kk & 3;
      const int ky = kpos / 3, kx = kpos - ky * 3;
      const size_t aof = (size_t)kk * 65536;
      const int    xof = ((icb64 * 4 * NPIX) << 4) + ((ky * 58 + kx) << 4);
      char* ba = ldA + buf * 18432;
      gload16(aSrc + aof,        ba);
      gload16(aSrc + aof + 8192, ba + 8192);
      gload16(bSrc + xof, ldB + buf * 18432);   // 2KB, wave-sets redundant
    };

#pragma unroll
    for (int pt = 0; pt < 2; ++pt) STAGE(pt, pt);
    asm volatile("s_waitcnt vmcnt(3)" ::: "memory");
    __builtin_amdgcn_s_barrier();
    __builtin_amdgcn_sched_barrier(0);

#pragma unroll
    for (int t = 0; t < 36; ++t) {
      const int cur = t % 3;
      const int nxt = (t + 2) % 3;
      if (t + 2 < 36) STAGE(t + 2, nxt);
      const char* bp = lds + cur * 18432;
      i32x4 av[4], bv;
#pragma unroll
      for (int i = 0; i < 4; ++i) av[i] = *(const i32x4*)(bp + aRd + i * 1024);
      bv = *(const i32x4*)(bp + bRd);
      __builtin_amdgcn_s_setprio(1);
#pragma unroll
      for (int i = 0; i < 4; ++i)
        acc[i] = __builtin_amdgcn_mfma_i32_16x16x64_i8(av[i], bv, acc[i], 0, 0, 0);
      __builtin_amdgcn_s_setprio(0);
      if (t < 34) asm volatile("s_waitcnt vmcnt(3)" ::: "memory");
      else        asm volatile("s_waitcnt vmcnt(0)" ::: "memory");
      __builtin_amdgcn_s_barrier();
      __builtin_amdgcn_sched_barrier(0);
    }
    __syncthreads();

    // epilogue: int8 LDS [4g][32 m][19 u32] -> reduce (512 thr: 1 u32 each)
    {
      const float r = sxp / ps[g];
#pragma unroll
      for (int i = 0; i < 4; ++i) {
        uint32_t pk = 0;
#pragma unroll
        for (int k = 0; k < 4; ++k) {
          float q = rintf((float)acc[i][k] * r);
          q = fminf(127.f, fmaxf(-128.f, q));
          pk |= ((uint32_t)(((int)q) & 255)) << (8 * k);
        }
        int m_l = mpos * 16 + rr;
        int oc4 = i * 4 + hi;
        *(uint32_t*)(lds + (g * 608 + m_l * 19 + oc4) * 4) = pk;
      }
    }
    __syncthreads();
    {
      const int m_l = tid >> 4;                 // 0..31
      const int oc4 = tid & 15;                 // u32 column
      float o[4] = {0.f, 0.f, 0.f, 0.f};
#pragma unroll
      for (int gg = 0; gg < 4; ++gg) {
        const float spg = ps[gg];
        uint32_t v2 = *(const uint32_t*)(lds + (gg * 608 + m_l * 19 + oc4) * 4);
#pragma unroll
        for (int b2 = 0; b2 < 4; ++b2)
          o[b2] += (float)((int)(int8_t)(v2 >> (8 * b2))) * spg;
      }
      int gm = m0 + m_l;
      int b = gm / 3136, rem = gm - b * 3136;
      int oy = rem / 56, ox = rem - oy * 56;
      float* ob = out + b * 802816 + oy * 56 + ox;
      const int occ = (ocb << 6) + (oc4 << 2);
#pragma unroll
      for (int j = 0; j < 4; ++j) ob[(occ + j) * 3136] = o[j];
    }
  }
}

extern "C" void kernel_launch(void* const* d_in, const int* in_sizes, int n_in,
                              void* d_out, int out_size, void* d_ws, size_t ws_size,
                              hipStream_t stream) {
  const float* x   = (const float*)d_in[0];   // [16,256,56,56]
  const float* w   = (const float*)d_in[1];   // [1024,256,3,3]
  const float* wsc = (const float*)d_in[2];   // [8]
  const float* ps  = (const float*)d_in[3];   // [4]
  float* out = (float*)d_out;                 // [16,256,56,56]
  int8_t* wq3 = (int8_t*)d_ws;
  int8_t* xt2 = (int8_t*)((char*)d_ws + WS_XT_OFF);

  prep_k<<<1024 + 928, 256, 0, stream>>>(w, wsc, wq3, x, xt2);
  conv_q_k<<<1664, 512, 0, stream>>>(xt2, wq3, ps, wsc, out);
}